// Round 5
// baseline (581.933 us; speedup 1.0000x reference)
//
#include <hip/hip_runtime.h>
#include <hip/hip_bf16.h>

// MoE top-2/8, T=4096, H=2048, FFN=1024.
//   router_conv (router + W1/W3/W2 fp32->bf16 convert, one grid)
//   compact     (1 block, ballot prefix)
//   upproj_8ph  (BM=256 BN=64x2 BK=64, 8 waves, 3-buf depth-2, 2-phase/K-tile,
//                counted vmcnt(6), raw barriers, setprio, chunk-XOR swizzle)
//   downproj_8ph(BM=256 BN=128, same skeleton)
//   combine

#define T_TOK 4096
#define H_DIM 2048
#define FFN_D 1024
#define NE    8

typedef __attribute__((ext_vector_type(8))) short          bf16x8;
typedef __attribute__((ext_vector_type(4))) float          f32x4;
typedef __attribute__((ext_vector_type(4))) unsigned short us4;

#define N4_PER_W ((size_t)NE * FFN_D * H_DIM / 4)   // 4,194,304 float4 per weight tensor
#define RB_ROUTER 1024u
#define CB_CONV   8192u     // W1+W3 convert blocks
#define CB_W2     4096u     // W2 convert blocks

__device__ __forceinline__ unsigned short f2bf(float f) {
  unsigned u = __builtin_bit_cast(unsigned, f);
  u += 0x7fffu + ((u >> 16) & 1u);
  return (unsigned short)(u >> 16);
}
__device__ __forceinline__ float bf2f(unsigned short u) {
  return __builtin_bit_cast(float, ((unsigned)u) << 16);
}
__device__ __forceinline__ us4 f4bf(float4 v) {
  union { us4 o; unsigned u[2]; } r;
  asm("v_cvt_pk_bf16_f32 %0, %1, %2" : "=v"(r.u[0]) : "v"(v.x), "v"(v.y));
  asm("v_cvt_pk_bf16_f32 %0, %1, %2" : "=v"(r.u[1]) : "v"(v.z), "v"(v.w));
  return r.o;
}
__device__ __forceinline__ void async16(const void* g, void* l) {
  __builtin_amdgcn_global_load_lds((const __attribute__((address_space(1))) void*)g,
                                   (__attribute__((address_space(3))) void*)l, 16, 0, 0);
}

// ---------------- K1: router + W1/W3/W2 converts, one grid ----
__global__ void router_conv_kernel(const float* __restrict__ x,
                                   const float* __restrict__ Wg,
                                   const float* __restrict__ bias,
                                   unsigned* __restrict__ epair,
                                   float* __restrict__ wpair,
                                   unsigned short* __restrict__ Xb,
                                   const float* __restrict__ W1, unsigned short* __restrict__ W1b,
                                   const float* __restrict__ W3, unsigned short* __restrict__ W3b,
                                   const float* __restrict__ W2, unsigned short* __restrict__ W2b) {
  if (blockIdx.x >= RB_ROUTER + CB_CONV) {
    // W2 convert: 4096 blocks x 1024 float4
    size_t b0 = (size_t)(blockIdx.x - RB_ROUTER - CB_CONV) * 1024;
#pragma unroll
    for (int k = 0; k < 4; k++) {
      size_t i = b0 + k * 256 + threadIdx.x;
      float4 v = ((const float4*)W2)[i];
      ((us4*)W2b)[i] = f4bf(v);
    }
    return;
  }
  if (blockIdx.x >= RB_ROUTER) {
    // W1/W3 convert: 8192 blocks x 1024 float4
    size_t b0 = (size_t)(blockIdx.x - RB_ROUTER) * 1024;
#pragma unroll
    for (int k = 0; k < 4; k++) {
      size_t i = b0 + k * 256 + threadIdx.x;
      const float* s; unsigned short* d;
      if (i < N4_PER_W) { s = W1; d = W1b; } else { s = W3; d = W3b; i -= N4_PER_W; }
      float4 v = ((const float4*)s)[i];
      ((us4*)d)[i] = f4bf(v);
    }
    return;
  }
  const int wv   = threadIdx.x >> 6;
  const int lane = threadIdx.x & 63;
  const int t    = blockIdx.x * 4 + wv;

  const float4* xr = (const float4*)(x + (size_t)t * H_DIM);
  us4*          xb = (us4*)(Xb + (size_t)t * H_DIM);

  float acc[NE];
#pragma unroll
  for (int e = 0; e < NE; e++) acc[e] = 0.f;

#pragma unroll
  for (int j = 0; j < 8; j++) {
    int i4 = j * 64 + lane;
    float4 v = xr[i4];
    xb[i4] = f4bf(v);
#pragma unroll
    for (int e = 0; e < NE; e++) {
      float4 w = ((const float4*)(Wg + e * H_DIM))[i4];
      acc[e] += v.x * w.x + v.y * w.y + v.z * w.z + v.w * w.w;
    }
  }
#pragma unroll
  for (int e = 0; e < NE; e++) {
#pragma unroll
    for (int m = 32; m >= 1; m >>= 1) acc[e] += __shfl_xor(acc[e], m, 64);
  }

  if (lane == 0) {
    float sig[NE], sc[NE];
#pragma unroll
    for (int e = 0; e < NE; e++) {
      sig[e] = 1.f / (1.f + expf(-acc[e]));
      sc[e]  = sig[e] + bias[e];
    }
    int i1 = 0; float v1 = sc[0];
#pragma unroll
    for (int e = 1; e < NE; e++) if (sc[e] > v1) { v1 = sc[e]; i1 = e; }
    int i2 = -1; float v2 = -1e30f;
#pragma unroll
    for (int e = 0; e < NE; e++) if (e != i1 && sc[e] > v2) { v2 = sc[e]; i2 = e; }
    float w1 = sig[i1], w2 = sig[i2];
    float s = w1 + w2;
    epair[t] = (unsigned)i1 | ((unsigned)i2 << 8);
    wpair[2 * t]     = w1 / s;
    wpair[2 * t + 1] = w2 / s;
  }
}

// ---------------- K2: compaction, ONE block, 8 waves ----
__global__ void compact_kernel(const unsigned* __restrict__ epair,
                               const float* __restrict__ wpair,
                               int* __restrict__ cnt,
                               int* __restrict__ base,
                               int* __restrict__ rows,
                               float* __restrict__ wts,
                               int* __restrict__ t2s) {
  const int e    = threadIdx.x >> 6;
  const int lane = threadIdx.x & 63;
  const unsigned long long ltmask = ((unsigned long long)1 << lane) - 1;
  __shared__ int cnts[NE];

  int count = 0;
  for (int c = 0; c < T_TOK; c += 64) {
    int t = c + lane;
    unsigned ep = epair[t];
    bool m1 = ((ep & 255u) == (unsigned)e);
    bool m2 = (((ep >> 8) & 255u) == (unsigned)e);
    unsigned long long b1 = __ballot(m1);
    if (m1) {
      int p = count + __popcll(b1 & ltmask);
      rows[e * T_TOK + p] = t;
      wts [e * T_TOK + p] = wpair[2 * t];
      t2s[2 * t] = (e << 12) | p;
    }
    count += __popcll(b1);
    unsigned long long b2 = __ballot(m2);
    if (m2) {
      int p = count + __popcll(b2 & ltmask);
      rows[e * T_TOK + p] = t;
      wts [e * T_TOK + p] = wpair[2 * t + 1];
      t2s[2 * t + 1] = (e << 12) | p;
    }
    count += __popcll(b2);
  }
  if (lane == 0) { cnts[e] = count; cnt[e] = count; }
  __syncthreads();
  if (threadIdx.x == 0) {
    int s = 0;
    for (int i = 0; i < NE; i++) { base[i] = s; s += cnts[i]; }
    base[NE] = s;
  }
}

// ---------------- K3: up-proj, 8-wave phase-split schedule ----
// BM=256 slots, BN=64 per mat (W1,W3), BK=64, 3 LDS buffers, depth-2 prefetch.
__launch_bounds__(512)
__global__ void upproj_8ph(const unsigned short* __restrict__ Xb,
                           const unsigned short* __restrict__ W1b,
                           const unsigned short* __restrict__ W3b,
                           const int* __restrict__ cnt,
                           const int* __restrict__ base,
                           const int* __restrict__ rows,
                           const float* __restrict__ wts,
                           unsigned short* __restrict__ G) {
  const int e  = blockIdx.z;
  const int m0 = blockIdx.y * 256;
  const int n0 = blockIdx.x * 64;
  const int ce = cnt[e];
  if (m0 >= ce) return;

  __shared__ __align__(16) unsigned short As [3][256 * 64];   // 96 KB
  __shared__ __align__(16) unsigned short B1s[3][64 * 64];    // 24 KB
  __shared__ __align__(16) unsigned short B3s[3][64 * 64];    // 24 KB
  __shared__ int   t_ids[256];
  __shared__ float w_lds[256];

  const int tid = threadIdx.x;
  if (tid < 256) {
    int i = m0 + tid;
    if (i < ce) { t_ids[tid] = rows[e * T_TOK + i]; w_lds[tid] = wts[e * T_TOK + i]; }
    else        { t_ids[tid] = 0;                   w_lds[tid] = 0.f; }
  }
  __syncthreads();     // also drains the rows/wts vmem loads -> vmcnt clean

  const int lane  = tid & 63;
  const int wv    = tid >> 6;           // 0..7
  const int srow8 = lane >> 3;          // 0..7: row-within-8 AND swizzle term
  const int scol  = ((lane & 7) ^ srow8) * 8;   // pre-swizzled global col (elems)

  // per-thread global source pointers (fixed; advance by K elems)
  const unsigned short* apA[4];
#pragma unroll
  for (int j = 0; j < 4; j++) {
    int r = j * 64 + wv * 8 + srow8;            // A-tile row 0..255
    apA[j] = Xb + (size_t)t_ids[r] * H_DIM + scol;
  }
  const size_t ebase = (size_t)e * FFN_D * H_DIM;
  const int rbw = wv * 8 + srow8;               // B-tile row 0..63
  const unsigned short* apB1 = W1b + ebase + (size_t)(n0 + rbw) * H_DIM + scol;
  const unsigned short* apB3 = W3b + ebase + (size_t)(n0 + rbw) * H_DIM + scol;

  const int wvM = wv >> 1;   // 0..3 : 64-row slice
  const int wvN = wv & 1;    // 0..1 : 32-col slice per mat
  const int fr  = lane & 15;
  const int hi  = lane >> 4;
  const int rx  = fr & 7;    // read-side swizzle term (= row&7 for all frag rows)

  f32x4 acc1[4][2], acc3[4][2];
#pragma unroll
  for (int mi = 0; mi < 4; mi++)
#pragma unroll
    for (int ni = 0; ni < 2; ni++) { acc1[mi][ni] = (f32x4)0.f; acc3[mi][ni] = (f32x4)0.f; }

#define UPS_A3(T, B) { int kk = (T) * 64;                      \
    async16(apA[0] + kk, &As[B][(  0 + wv * 8) * 64]);         \
    async16(apA[1] + kk, &As[B][( 64 + wv * 8) * 64]);         \
    async16(apA[2] + kk, &As[B][(128 + wv * 8) * 64]); }
#define UPS_AB(T, B) { int kk = (T) * 64;                      \
    async16(apA[3] + kk, &As[B][(192 + wv * 8) * 64]);         \
    async16(apB1 + kk,  &B1s[B][(wv * 8) * 64]);               \
    async16(apB3 + kk,  &B3s[B][(wv * 8) * 64]); }

  // prologue: tiles 0 and 1 in flight, wait tile 0 (6 newest stay outstanding)
  UPS_A3(0, 0) UPS_AB(0, 0)
  UPS_A3(1, 1) UPS_AB(1, 1)
  asm volatile("s_waitcnt vmcnt(6)" ::: "memory");
  __builtin_amdgcn_s_barrier();

  for (int t = 0; t < H_DIM / 64; ++t) {
    const int  cb = t % 3;
    const int  nb = (t + 2) % 3;
    const bool pf = (t + 2 < H_DIM / 64);

    // -------- phase 1 : ksub 0 --------
    if (pf) UPS_A3(t + 2, nb)
    bf16x8 a[4], b1[2], b3[2];
    {
      const int c = ((0 + hi) ^ rx) * 8;
#pragma unroll
      for (int mi = 0; mi < 4; mi++)
        a[mi] = *(const bf16x8*)&As[cb][(wvM * 64 + mi * 16 + fr) * 64 + c];
#pragma unroll
      for (int ni = 0; ni < 2; ni++) {
        b1[ni] = *(const bf16x8*)&B1s[cb][(wvN * 32 + ni * 16 + fr) * 64 + c];
        b3[ni] = *(const bf16x8*)&B3s[cb][(wvN * 32 + ni * 16 + fr) * 64 + c];
      }
    }
    __builtin_amdgcn_sched_barrier(0);
    __builtin_amdgcn_s_barrier();
    asm volatile("s_waitcnt lgkmcnt(0)" ::: "memory");
    __builtin_amdgcn_sched_barrier(0);
    __builtin_amdgcn_s_setprio(1);
#pragma unroll
    for (int mi = 0; mi < 4; mi++)
#pragma unroll
      for (int ni = 0; ni < 2; ni++) {
        acc1[mi][ni] = __builtin_amdgcn_mfma_f32_16x16x32_bf16(a[mi], b1[ni], acc1[mi][ni], 0, 0, 0);
        acc3[mi][ni] = __builtin_amdgcn_mfma_f32_16x16x32_bf16(a[mi], b3[ni], acc3[mi][ni], 0, 0, 0);
      }
    __builtin_amdgcn_s_setprio(0);
    __builtin_amdgcn_sched_barrier(0);
    __builtin_amdgcn_s_barrier();

    // -------- phase 2 : ksub 1 --------
    if (pf) UPS_AB(t + 2, nb)
    {
      const int c = ((4 + hi) ^ rx) * 8;
#pragma unroll
      for (int mi = 0; mi < 4; mi++)
        a[mi] = *(const bf16x8*)&As[cb][(wvM * 64 + mi * 16 + fr) * 64 + c];
#pragma unroll
      for (int ni = 0; ni < 2; ni++) {
        b1[ni] = *(const bf16x8*)&B1s[cb][(wvN * 32 + ni * 16 + fr) * 64 + c];
        b3[ni] = *(const bf16x8*)&B3s[cb][(wvN * 32 + ni * 16 + fr) * 64 + c];
      }
    }
    __builtin_amdgcn_sched_barrier(0);
    if (pf) asm volatile("s_waitcnt vmcnt(6)" ::: "memory");  // tile t+1 landed
    else    asm volatile("s_waitcnt vmcnt(0)" ::: "memory");
    __builtin_amdgcn_s_barrier();
    asm volatile("s_waitcnt lgkmcnt(0)" ::: "memory");
    __builtin_amdgcn_sched_barrier(0);
    __builtin_amdgcn_s_setprio(1);
#pragma unroll
    for (int mi = 0; mi < 4; mi++)
#pragma unroll
      for (int ni = 0; ni < 2; ni++) {
        acc1[mi][ni] = __builtin_amdgcn_mfma_f32_16x16x32_bf16(a[mi], b1[ni], acc1[mi][ni], 0, 0, 0);
        acc3[mi][ni] = __builtin_amdgcn_mfma_f32_16x16x32_bf16(a[mi], b3[ni], acc3[mi][ni], 0, 0, 0);
      }
    __builtin_amdgcn_s_setprio(0);
    __builtin_amdgcn_sched_barrier(0);
    __builtin_amdgcn_s_barrier();
  }
#undef UPS_A3
#undef UPS_AB

  const int be = base[e];
#pragma unroll
  for (int mi = 0; mi < 4; mi++)
#pragma unroll
    for (int ni = 0; ni < 2; ni++)
#pragma unroll
      for (int r = 0; r < 4; r++) {
        int row = wvM * 64 + mi * 16 + hi * 4 + r;
        int col = wvN * 32 + ni * 16 + fr;
        int i = m0 + row;
        if (i < ce) {
          float h1 = acc1[mi][ni][r];
          float h3 = acc3[mi][ni][r];
          float g  = h1 / (1.f + expf(-h1)) * h3 * w_lds[row];
          G[(size_t)(be + i) * FFN_D + n0 + col] = f2bf(g);
        }
      }
}

// ---------------- K4: down-proj, same skeleton. BM=256, BN=128, BK=64 ----
__launch_bounds__(512)
__global__ void downproj_8ph(const unsigned short* __restrict__ G,
                             const unsigned short* __restrict__ W2b,
                             const int* __restrict__ cnt,
                             const int* __restrict__ base,
                             unsigned short* __restrict__ Gd) {
  const int e  = blockIdx.z;
  const int m0 = blockIdx.y * 256;
  const int n0 = blockIdx.x * 128;
  const int ce = cnt[e];
  if (m0 >= ce) return;
  const int be = base[e];

  __shared__ __align__(16) unsigned short As[3][256 * 64];   // 96 KB
  __shared__ __align__(16) unsigned short Bs[3][128 * 64];   // 48 KB

  const int tid   = threadIdx.x;
  const int lane  = tid & 63;
  const int wv    = tid >> 6;
  const int srow8 = lane >> 3;
  const int scol  = ((lane & 7) ^ srow8) * 8;

  const unsigned short* apA[4];
#pragma unroll
  for (int j = 0; j < 4; j++) {
    int rr = m0 + j * 64 + wv * 8 + srow8;
    if (rr >= ce) rr = ce - 1;
    apA[j] = G + (size_t)(be + rr) * FFN_D + scol;
  }
  const unsigned short* apB[2];
#pragma unroll
  for (int jb = 0; jb < 2; jb++)
    apB[jb] = W2b + (size_t)e * H_DIM * FFN_D
                  + (size_t)(n0 + jb * 64 + wv * 8 + srow8) * FFN_D + scol;

  const int wvM = wv >> 1;   // 64-row slice
  const int wvN = wv & 1;    // 64-col slice
  const int fr  = lane & 15;
  const int hi  = lane >> 4;
  const int rx  = fr & 7;

  f32x4 acc[4][4];
#pragma unroll
  for (int mi = 0; mi < 4; mi++)
#pragma unroll
    for (int ni = 0; ni < 4; ni++) acc[mi][ni] = (f32x4)0.f;

#define DNS_A3(T, B) { int kk = (T) * 64;                      \
    async16(apA[0] + kk, &As[B][(  0 + wv * 8) * 64]);         \
    async16(apA[1] + kk, &As[B][( 64 + wv * 8) * 64]);         \
    async16(apA[2] + kk, &As[B][(128 + wv * 8) * 64]); }
#define DNS_AB(T, B) { int kk = (T) * 64;                      \
    async16(apA[3] + kk, &As[B][(192 + wv * 8) * 64]);         \
    async16(apB[0] + kk, &Bs[B][(  0 + wv * 8) * 64]);         \
    async16(apB[1] + kk, &Bs[B][( 64 + wv * 8) * 64]); }

  DNS_A3(0, 0) DNS_AB(0, 0)
  DNS_A3(1, 1) DNS_AB(1, 1)
  asm volatile("s_waitcnt vmcnt(6)" ::: "memory");
  __builtin_amdgcn_s_barrier();

  for (int t = 0; t < FFN_D / 64; ++t) {
    const int  cb = t % 3;
    const int  nb = (t + 2) % 3;
    const bool pf = (t + 2 < FFN_D / 64);

    // -------- phase 1 : ksub 0 --------
    if (pf) DNS_A3(t + 2, nb)
    bf16x8 a[4], b[4];
    {
      const int c = ((0 + hi) ^ rx) * 8;
#pragma unroll
      for (int mi = 0; mi < 4; mi++)
        a[mi] = *(const bf16x8*)&As[cb][(wvM * 64 + mi * 16 + fr) * 64 + c];
#pragma unroll
      for (int ni = 0; ni < 4; ni++)
        b[ni] = *(const bf16x8*)&Bs[cb][(wvN * 64 + ni * 16 + fr) * 64 + c];
    }
    __builtin_amdgcn_sched_barrier(0);
    __builtin_amdgcn_s_barrier();
    asm volatile("s_waitcnt lgkmcnt(0)" ::: "memory");
    __builtin_amdgcn_sched_barrier(0);
    __builtin_amdgcn_s_setprio(1);
#pragma unroll
    for (int mi = 0; mi < 4; mi++)
#pragma unroll
      for (int ni = 0; ni < 4; ni++)
        acc[mi][ni] = __builtin_amdgcn_mfma_f32_16x16x32_bf16(a[mi], b[ni], acc[mi][ni], 0, 0, 0);
    __builtin_amdgcn_s_setprio(0);
    __builtin_amdgcn_sched_barrier(0);
    __builtin_amdgcn_s_barrier();

    // -------- phase 2 : ksub 1 --------
    if (pf) DNS_AB(t + 2, nb)
    {
      const int c = ((4 + hi) ^ rx) * 8;
#pragma unroll
      for (int mi = 0; mi < 4; mi++)
        a[mi] = *(const bf16x8*)&As[cb][(wvM * 64 + mi * 16 + fr) * 64 + c];
#pragma unroll
      for (int ni = 0; ni < 4; ni++)
        b[ni] = *(const bf16x8*)&Bs[cb][(wvN * 64 + ni * 16 + fr) * 64 + c];
    }
    __builtin_amdgcn_sched_barrier(0);
    if (pf) asm volatile("s_waitcnt vmcnt(6)" ::: "memory");
    else    asm volatile("s_waitcnt vmcnt(0)" ::: "memory");
    __builtin_amdgcn_s_barrier();
    asm volatile("s_waitcnt lgkmcnt(0)" ::: "memory");
    __builtin_amdgcn_sched_barrier(0);
    __builtin_amdgcn_s_setprio(1);
#pragma unroll
    for (int mi = 0; mi < 4; mi++)
#pragma unroll
      for (int ni = 0; ni < 4; ni++)
        acc[mi][ni] = __builtin_amdgcn_mfma_f32_16x16x32_bf16(a[mi], b[ni], acc[mi][ni], 0, 0, 0);
    __builtin_amdgcn_s_setprio(0);
    __builtin_amdgcn_sched_barrier(0);
    __builtin_amdgcn_s_barrier();
  }
#undef DNS_A3
#undef DNS_AB

#pragma unroll
  for (int mi = 0; mi < 4; mi++)
#pragma unroll
    for (int ni = 0; ni < 4; ni++)
#pragma unroll
      for (int r = 0; r < 4; r++) {
        int row = wvM * 64 + mi * 16 + hi * 4 + r;
        int col = wvN * 64 + ni * 16 + fr;
        int i = m0 + row;
        if (i < ce)
          Gd[(size_t)(be + i) * H_DIM + n0 + col] = f2bf(acc[mi][ni][r]);
      }
}

// ---------------- K5: combine out[t] = Gd[slot1] + Gd[slot2] ----
__global__ void combine_kernel(const unsigned short* __restrict__ Gd,
                               const int* __restrict__ base,
                               const int* __restrict__ tok2slot,
                               float* __restrict__ out) {
  const int t = blockIdx.x;
  const int v1 = tok2slot[2 * t], v2 = tok2slot[2 * t + 1];
  const int s1 = base[v1 >> 12] + (v1 & 4095);
  const int s2 = base[v2 >> 12] + (v2 & 4095);
  const us4* r1 = (const us4*)(Gd + (size_t)s1 * H_DIM);
  const us4* r2 = (const us4*)(Gd + (size_t)s2 * H_DIM);
  float4* o = (float4*)(out + (size_t)t * H_DIM);
#pragma unroll
  for (int j = 0; j < 2; j++) {
    int i = j * 256 + threadIdx.x;
    us4 a = r1[i], b = r2[i];
    float4 r;
    r.x = bf2f(a.x) + bf2f(b.x);
    r.y = bf2f(a.y) + bf2f(b.y);
    r.z = bf2f(a.z) + bf2f(b.z);
    r.w = bf2f(a.w) + bf2f(b.w);
    o[i] = r;
  }
}

// ---------------- Launch ----------------
extern "C" void kernel_launch(void* const* d_in, const int* in_sizes, int n_in,
                              void* d_out, int out_size, void* d_ws, size_t ws_size,
                              hipStream_t stream) {
  (void)in_sizes; (void)n_in; (void)out_size; (void)ws_size;
  const float* x    = (const float*)d_in[0];
  const float* Wg   = (const float*)d_in[1];
  const float* W1   = (const float*)d_in[2];
  const float* W2   = (const float*)d_in[3];
  const float* W3   = (const float*)d_in[4];
  const float* bias = (const float*)d_in[5];
  float* out = (float*)d_out;

  char* ws = (char*)d_ws;
  const size_t OFF_CNT   = 0;
  const size_t OFF_BASE  = 64;
  const size_t OFF_T2S   = 1024;                       // 32 KB
  const size_t OFF_ROWS  = 65536;                      // 128 KB
  const size_t OFF_WTS   = OFF_ROWS + 131072;          // 128 KB
  const size_t OFF_EPAIR = OFF_WTS + 131072;           // 16 KB
  const size_t OFF_WPAIR = OFF_EPAIR + 16384;          // 32 KB
  const size_t OFF_XB    = 1048576;                    // 16 MB
  const size_t OFF_W1B   = OFF_XB + 16777216;          // 32 MB (Gd aliases after upproj)
  const size_t OFF_W3B   = OFF_W1B + 33554432;         // 32 MB
  const size_t OFF_G     = OFF_W3B + 33554432;         // 16 MB
  const size_t OFF_W2B   = OFF_G + 16777216;           // 32 MB
  // total ~129 MB (proven)

  int*   cnt   = (int*)(ws + OFF_CNT);
  int*   base  = (int*)(ws + OFF_BASE);
  int*   t2s   = (int*)(ws + OFF_T2S);
  int*   rows  = (int*)(ws + OFF_ROWS);
  float* wts   = (float*)(ws + OFF_WTS);
  unsigned* epair = (unsigned*)(ws + OFF_EPAIR);
  float* wpair = (float*)(ws + OFF_WPAIR);
  unsigned short* Xb  = (unsigned short*)(ws + OFF_XB);
  unsigned short* W1b = (unsigned short*)(ws + OFF_W1B);
  unsigned short* W3b = (unsigned short*)(ws + OFF_W3B);
  unsigned short* W2b = (unsigned short*)(ws + OFF_W2B);
  unsigned short* Gd  = (unsigned short*)(ws + OFF_W1B);  // alias: W1b dead after upproj
  unsigned short* G   = (unsigned short*)(ws + OFF_G);

  router_conv_kernel<<<RB_ROUTER + CB_CONV + CB_W2, 256, 0, stream>>>(
      x, Wg, bias, epair, wpair, Xb, W1, W1b, W3, W3b, W2, W2b);

  compact_kernel<<<1, 512, 0, stream>>>(epair, wpair, cnt, base, rows, wts, t2s);

  dim3 g2(FFN_D / 64, T_TOK / 256, NE);
  upproj_8ph<<<g2, 512, 0, stream>>>(Xb, W1b, W3b, cnt, base, rows, wts, G);

  dim3 g3(H_DIM / 128, T_TOK / 256, NE);
  downproj_8ph<<<g3, 512, 0, stream>>>(G, W2b, cnt, base, Gd);

  combine_kernel<<<T_TOK, 256, 0, stream>>>(Gd, base, t2s, out);
}